// Round 8
// baseline (259.756 us; speedup 1.0000x reference)
//
#include <hip/hip_runtime.h>
#include <hip/hip_bf16.h>

#define NB 32
#define NN 128
#define NE 16256
#define ND 64
#define NHID 128
#define NM 128
#define NOH 256
#define NT 2
#define EHALF 8128
#define NTILE 127        // 64-edge tiles per half (127*64 == 8128 exactly)
#define TILE_E 64

typedef short s16x8 __attribute__((ext_vector_type(8)));
typedef short s16x4 __attribute__((ext_vector_type(4)));
typedef float f32x4 __attribute__((ext_vector_type(4)));

#define MFMA16(a, b, c) __builtin_amdgcn_mfma_f32_16x16x32_bf16((a), (b), (c), 0, 0, 0)

// ---- ws layout (bytes) ----
// partial: bf16 [512][m=128][n=128]
#define PARTIAL_SZ ((size_t)512 * 128 * 128 * 2)          // 16,777,216
#define WS_RS      (PARTIAL_SZ)                           // ushort[NE][128]
#define RS_SZ      ((size_t)NE * 128 * 2)                 //  4,161,536
#define WS_RRT     (WS_RS + RS_SZ)                        // ushort[128][NE]
#define RRT_SZ     ((size_t)128 * NE * 2)                 //  4,161,536
#define WS_IWA     (WS_RRT + RRT_SZ)                      // ushort[b][half][it][h=128][n=128]
#define IWA_SZ     ((size_t)NB * 2 * 2 * 128 * 128 * 2)   //  8,388,608
// total = 33,488,896 B (proven to fit ws)

__device__ __forceinline__ ushort f2bf(float x) {
    uint u = __float_as_uint(x);
    return (ushort)((u + 0x7fffu + ((u >> 16) & 1u)) >> 16);
}
__device__ __forceinline__ float bf2f(ushort h) {
    return __uint_as_float(((uint)h) << 16);
}
__device__ __forceinline__ float4 ldg4(const float* p) {
    return *reinterpret_cast<const float4*>(p);
}
// XOR-swizzle within a row (G4): byte ^= (row&7)<<4
__device__ __forceinline__ char* swz(void* base, int row, int rowBytes, int bir) {
    return (char*)base + row * rowBytes + (bir ^ ((row & 7) << 4));
}
__device__ __forceinline__ const char* swzc(const void* base, int row, int rowBytes, int bir) {
    return (const char*)base + row * rowBytes + (bir ^ ((row & 7) << 4));
}
// async 16B global->LDS (dest is lane-linear; source pre-swizzled per G21)
__device__ __forceinline__ void gload16(const void* g, void* l) {
    __builtin_amdgcn_global_load_lds(
        (const __attribute__((address_space(1))) void*)g,
        (__attribute__((address_space(3))) void*)l, 16, 0, 0);
}
// volatile 16B load: compiler must NOT hoist out of the tile loop
__device__ __forceinline__ s16x8 ldv8(const ushort* p) {
    return *(const volatile s16x8*)p;
}

// ---------------------------------------------------------------------------
// k_pre: fused conversions + inpWA precompute.
// blocks 0..126: rrT transpose+convert; 127..253: rs convert;
// blocks 254..381: inpWA[b][half][it] = (inp[b] @ WA^T) in bf16 [h][n]
// ---------------------------------------------------------------------------
__global__ __launch_bounds__(256)
void k_pre(const float* __restrict__ inputs,
           const float* __restrict__ rel_rec, const float* __restrict__ rel_send,
           const float* __restrict__ w1, const float* __restrict__ w3,
           char* __restrict__ ws)
{
    ushort* rs  = (ushort*)(ws + WS_RS);
    ushort* rrT = (ushort*)(ws + WS_RRT);
    const int t = threadIdx.x;
    const int blk = blockIdx.x;
    __shared__ float lds[128][65];

    if (blk < 127) {                       // rrT: transpose rel_rec -> [n][e] bf16
        const int eb = blk;
        for (int nh = 0; nh < 2; ++nh) {
            __syncthreads();
            for (int i = t; i < 128 * 64; i += 256) {
                int e = i >> 6, n = i & 63;
                lds[e][n] = rel_rec[(size_t)(eb * 128 + e) * 128 + nh * 64 + n];
            }
            __syncthreads();
            for (int i = t; i < 64 * 128; i += 256) {
                int n = i >> 7, e = i & 127;
                rrT[(size_t)(nh * 64 + n) * NE + eb * 128 + e] = f2bf(lds[e][n]);
            }
        }
    } else if (blk < 254) {                // rs: straight convert
        const int eb = blk - 127;
        const float4* src = (const float4*)(rel_send + (size_t)eb * 16384);
        for (int i = t; i < 4096; i += 256) {
            float4 v = src[i];
            ushort4 o;
            o.x = f2bf(v.x); o.y = f2bf(v.y); o.z = f2bf(v.z); o.w = f2bf(v.w);
            *(ushort4*)(rs + (size_t)eb * 16384 + (size_t)i * 4) = o;
        }
    } else {                               // inpWA precompute (MFMA)
        ushort* iwa = (ushort*)(ws + WS_IWA);
        const int wg = blk - 254;          // 0..127
        const int b = wg >> 2, half = (wg >> 1) & 1, it = wg & 1;
        const float* WA  = (half ? w3 : w1) + (size_t)it * NHID * ND;
        const float* inp = inputs + (size_t)b * NN * ND;
        ushort* dst = iwa + (size_t)wg * NHID * NN;    // [h][n]

        const int lane = t & 63, wave = t >> 6;
        const int l16 = lane & 15, l4 = lane >> 4;

        for (int hh = 0; hh < 2; ++hh) {
            const int ht = wave * 2 + hh;
            s16x8 bf[2];
#pragma unroll
            for (int ks = 0; ks < 2; ++ks) {
                const float* p = WA + (size_t)(ht * 16 + l16) * ND + ks * 32 + l4 * 8;
                float4 u = ldg4(p), v = ldg4(p + 4);
                s16x8 f;
                f[0] = (short)f2bf(u.x); f[1] = (short)f2bf(u.y);
                f[2] = (short)f2bf(u.z); f[3] = (short)f2bf(u.w);
                f[4] = (short)f2bf(v.x); f[5] = (short)f2bf(v.y);
                f[6] = (short)f2bf(v.z); f[7] = (short)f2bf(v.w);
                bf[ks] = f;
            }
            for (int nt = 0; nt < 8; ++nt) {
                s16x8 af[2];
#pragma unroll
                for (int ks = 0; ks < 2; ++ks) {
                    const float* p = inp + (size_t)(nt * 16 + l16) * ND + ks * 32 + l4 * 8;
                    float4 u = ldg4(p), v = ldg4(p + 4);
                    s16x8 f;
                    f[0] = (short)f2bf(u.x); f[1] = (short)f2bf(u.y);
                    f[2] = (short)f2bf(u.z); f[3] = (short)f2bf(u.w);
                    f[4] = (short)f2bf(v.x); f[5] = (short)f2bf(v.y);
                    f[6] = (short)f2bf(v.z); f[7] = (short)f2bf(v.w);
                    af[ks] = f;
                }
                f32x4 c = (f32x4){0.f, 0.f, 0.f, 0.f};
                c = MFMA16(af[0], bf[0], c);
                c = MFMA16(af[1], bf[1], c);
                s16x4 o;
                o[0] = (short)f2bf(c[0]); o[1] = (short)f2bf(c[1]);
                o[2] = (short)f2bf(c[2]); o[3] = (short)f2bf(c[3]);
                *(s16x4*)&dst[(size_t)(ht * 16 + l16) * NN + nt * 16 + l4 * 4] = o;
            }
        }
    }
}

// ---------------------------------------------------------------------------
// k_edge: grid 512 = b*16 + half*8 + chunk(8). block 512 (8 waves).
// 72.5 KB LDS, target 2 blocks/CU (4 waves/SIMD). Two barriers per tile.
// Register budget: unified VGPR+AGPR per wave must stay ~<= 104 so that
// 4 waves/SIMD fit the measured ~416-480 reg pool (rounds 3/4/7 bracketing):
//   persistent: wB 32 + agg 32(AGPR) = 64
//   H phase: + wIW-transient 16 (volatile reload per tile per it) + a-pair 8
//   M phase: + a 8 + macc/rtv/bb ~20
// ---------------------------------------------------------------------------
__global__ __launch_bounds__(512, 2)
void k_edge(const float* __restrict__ rel_type,
            const float* __restrict__ b1, const float* __restrict__ b2,
            const float* __restrict__ b3, const float* __restrict__ b4,
            const float* __restrict__ w2, const float* __restrict__ w4,
            char* __restrict__ ws)
{
    const ushort* rsg = (const ushort*)(ws + WS_RS);
    const ushort* rrT = (const ushort*)(ws + WS_RRT);
    const ushort* iwa = (const ushort*)(ws + WS_IWA);
    ushort* partial   = (ushort*)ws;

    const int tid  = threadIdx.x;
    const int wave = tid >> 6;
    const int lane = tid & 63;
    const int l16  = lane & 15;
    const int l4   = lane >> 4;

    const int wg    = blockIdx.x;
    const int b     = wg >> 4;
    const int half  = (wg >> 3) & 1;
    const int chunk = wg & 7;

    const float* BA    = half ? b3 : b1;
    const float* BB    = half ? b4 : b2;
    const float* WBsrc = half ? w4 : w2;

    __shared__ ushort H_s[2][64 * 128];   // 32 KB (it), rows 256B, swz (er&7)<<4
    __shared__ ushort rs_s[64 * 128];     // 16 KB, rows 256B, stored pre-swizzled
    __shared__ ushort rr_s[128 * 64];     // 16 KB, rows 128B, stored pre-swizzled
    __shared__ ushort Mt_s[8][16 * 32];   //  8 KB, wave-private, rows 64B
    __shared__ float  rt_s[128];          // 0.5 KB

    // wIW reload base (streamed per tile; NOT register-persistent)
    const ushort* iwb = iwa + (size_t)((b * 2 + half) * 2) * NHID * NN +
                        (size_t)(wave * 16 + l16) * NN + l4 * 8;

    // persistent: wB fragments (32) + biases
    s16x8 wB[2][4];
#pragma unroll
    for (int it = 0; it < 2; ++it)
#pragma unroll
        for (int ks = 0; ks < 4; ++ks) {
            const float* p = WBsrc + (size_t)(it * NM + wave * 16 + l16) * NHID + ks * 32 + l4 * 8;
            float4 u = ldg4(p), v = ldg4(p + 4);
            s16x8 f;
            f[0] = (short)f2bf(u.x); f[1] = (short)f2bf(u.y);
            f[2] = (short)f2bf(u.z); f[3] = (short)f2bf(u.w);
            f[4] = (short)f2bf(v.x); f[5] = (short)f2bf(v.y);
            f[6] = (short)f2bf(v.z); f[7] = (short)f2bf(v.w);
            wB[it][ks] = f;
        }
    float biasA[2] = {BA[wave * 16 + l16], BA[NHID + wave * 16 + l16]};
    float biasB[2] = {BB[wave * 16 + l16], BB[NM + wave * 16 + l16]};

    f32x4 agg[8];
#pragma unroll
    for (int r = 0; r < 8; ++r) agg[r] = (f32x4){0.f, 0.f, 0.f, 0.f};

    const int t0 = chunk * 16;
    const int t1 = (t0 + 16 < NTILE) ? (t0 + 16) : NTILE;

    // ---- prologue: stage rs(t0): slot i=(e,c) holds global chunk c^(e&7) ----
    {
        const int ebase0 = half * EHALF + t0 * TILE_E;
#pragma unroll
        for (int s = 0; s < 2; ++s) {
            const int i = s * 512 + tid;
            const int e = i >> 4, c = lane & 15;
            const int cp = c ^ (e & 7);
            gload16(rsg + (size_t)(ebase0 + e) * 128 + cp * 8, (char*)rs_s + i * 16);
        }
    }
    __syncthreads();

    for (int t = t0; t < t1; ++t) {
        const int ebase = half * EHALF + t * TILE_E;
        const bool do_next = (t + 1) < t1;

        // ---- Segment A ----
        // (a) issue rr(t) -> rr_s: slot j=(n,c) holds global chunk c^(n&7)
#pragma unroll
        for (int s = 0; s < 2; ++s) {
            const int j = s * 512 + tid;
            const int n = j >> 3, c = lane & 7;
            const int cp = c ^ (n & 7);
            gload16(rrT + (size_t)n * NE + ebase + cp * 8, (char*)rr_s + j * 16);
        }
        // (b) rt stage (contiguous)
        if (tid < 128)
            rt_s[tid] = rel_type[((size_t)b * NE + ebase + (tid >> 1)) * NT + (tid & 1)];

        // (c) H-phase: it-outer, wIW streamed (16 regs), a-frags paired (8 regs)
#pragma unroll
        for (int it = 0; it < 2; ++it) {
            const ushort* wp = iwb + (size_t)it * NHID * NN;
            s16x8 w0 = ldv8(wp);
            s16x8 w1 = ldv8(wp + 32);
            s16x8 w2v = ldv8(wp + 64);
            s16x8 w3v = ldv8(wp + 96);
#pragma unroll
            for (int et = 0; et < 4; ++et) {
                const int erow = et * 16 + l16;
                f32x4 c = (f32x4){0.f, 0.f, 0.f, 0.f};
                {
                    s16x8 a0 = *(const s16x8*)swzc(rs_s, erow, 256, (0 * 32 + l4 * 8) * 2);
                    s16x8 a1 = *(const s16x8*)swzc(rs_s, erow, 256, (1 * 32 + l4 * 8) * 2);
                    __builtin_amdgcn_s_setprio(1);
                    c = MFMA16(a0, w0, c);
                    c = MFMA16(a1, w1, c);
                    __builtin_amdgcn_s_setprio(0);
                }
                {
                    s16x8 a2 = *(const s16x8*)swzc(rs_s, erow, 256, (2 * 32 + l4 * 8) * 2);
                    s16x8 a3 = *(const s16x8*)swzc(rs_s, erow, 256, (3 * 32 + l4 * 8) * 2);
                    __builtin_amdgcn_s_setprio(1);
                    c = MFMA16(a2, w2v, c);
                    c = MFMA16(a3, w3v, c);
                    __builtin_amdgcn_s_setprio(0);
                }
#pragma unroll
                for (int r = 0; r < 4; ++r) {
                    const int er = et * 16 + l4 * 4 + r;
                    *(ushort*)swz(&H_s[it][0], er, 256, (wave * 16 + l16) * 2) =
                        f2bf(fmaxf(c[r] + biasA[it], 0.f));
                }
            }
        }
        __syncthreads();                                   // bar1

        // ---- Segment B ----
        // (d) issue rs(t+1) -> rs_s (rs(t) fully consumed in segment A)
        if (do_next) {
            const int ebn = ebase + TILE_E;
#pragma unroll
            for (int s = 0; s < 2; ++s) {
                const int i = s * 512 + tid;
                const int e = i >> 4, c = lane & 15;
                const int cp = c ^ (e & 7);
                gload16(rsg + (size_t)(ebn + e) * 128 + cp * 8, (char*)rs_s + i * 16);
            }
        }

        // (e) M + agg in two K=32 passes
        char* mtw = (char*)&Mt_s[wave][0];
#pragma unroll
        for (int p = 0; p < 2; ++p) {
#pragma unroll
            for (int eq = 0; eq < 2; ++eq) {
                const int etq = p * 2 + eq;
                const int e = etq * 16 + l16;
                float2 rtv[4];
#pragma unroll
                for (int r = 0; r < 4; ++r)
                    rtv[r] = *(const float2*)&rt_s[(etq * 16 + l4 * 4 + r) * 2];
                float macc[4] = {0.f, 0.f, 0.f, 0.f};
#pragma unroll
                for (int it = 0; it < 2; ++it) {
                    f32x4 c = (f32x4){0.f, 0.f, 0.f, 0.f};
                    __builtin_amdgcn_s_setprio(1);
#pragma unroll
                    for (int ks = 0; ks < 4; ++ks) {
                        s16x8 a = *(const s16x8*)swzc(&H_s[it][0], e, 256, (ks * 32 + l4 * 8) * 2);
                        c = MFMA16(a, wB[it][ks], c);
                    }
                    __builtin_amdgcn_s_setprio(0);
#pragma unroll
                    for (int r = 0; r < 4; ++r)
                        macc[r] += fmaxf(c[r] + biasB[it], 0.f) * (it ? rtv[r].y : rtv[r].x);
                }
                // Mt write: row l16 (64B), byte (eq*32 + l4*8) ^ ((m&3)<<4)
                s16x4 v;
                v[0] = (short)f2bf(macc[0]);
                v[1] = (short)f2bf(macc[1]);
                v[2] = (short)f2bf(macc[2]);
                v[3] = (short)f2bf(macc[3]);
                *(s16x4*)(mtw + l16 * 64 + ((eq * 32 + l4 * 8) ^ ((l16 & 3) << 4))) = v;
            }
            // B-fragment read (same wave wrote it; DS ops in-order per wave)
            s16x8 bb = *(const s16x8*)(mtw + l16 * 64 + ((l4 * 16) ^ ((l16 & 3) << 4)));
            __builtin_amdgcn_s_setprio(1);
#pragma unroll
            for (int nt = 0; nt < 8; ++nt) {
                const int n = nt * 16 + l16;
                s16x8 a = *(const s16x8*)swzc(rr_s, n, 128, (p * 32 + l4 * 8) * 2);
                agg[nt] = MFMA16(a, bb, agg[nt]);
            }
            __builtin_amdgcn_s_setprio(0);
        }
        __syncthreads();                                   // bar2
    }

    // store bf16 partialT [wg][m][n] (vector s16x4)
    {
        ushort* dst = partial + (size_t)wg * (NN * NM);
        const int m = wave * 16 + l16;
#pragma unroll
        for (int nt = 0; nt < 8; ++nt) {
            s16x4 v;
            v[0] = (short)f2bf(agg[nt][0]);
            v[1] = (short)f2bf(agg[nt][1]);
            v[2] = (short)f2bf(agg[nt][2]);
            v[3] = (short)f2bf(agg[nt][3]);
            *(s16x4*)&dst[(size_t)m * NN + nt * 16 + l4 * 4] = v;
        }
    }
}

// ---------------------------------------------------------------------------
// k_out: reduce 16 bf16 partials -> node MLP 128->256->256->64 + residual
// ---------------------------------------------------------------------------
__global__ __launch_bounds__(256)
void k_out(const ushort* __restrict__ partial,
           const float* __restrict__ inputs,
           const float* __restrict__ ow1, const float* __restrict__ ob1,
           const float* __restrict__ ow2, const float* __restrict__ ob2,
           const float* __restrict__ ow3, const float* __restrict__ ob3,
           float* __restrict__ out)
{
    const int t  = threadIdx.x;
    const int wg = blockIdx.x;      // 0..255
    const int b  = wg >> 3;
    const int n0 = (wg & 7) * 16;

    __shared__ float xr[16 * NM];
    __shared__ float h1[16 * NOH];
    __shared__ float h2[16 * NOH];

    // reduce 16 partials (transposed layout [m][n])
    for (int u = t; u < 512; u += 256) {
        const int m = u >> 2, g = u & 3;
        float s0 = 0.f, s1 = 0.f, s2 = 0.f, s3 = 0.f;
#pragma unroll
        for (int c = 0; c < 16; ++c) {
            const ushort* p = partial + ((size_t)(b * 16 + c)) * (NN * NM) +
                              (size_t)m * NN + n0 + g * 4;
            s16x4 v = *(const s16x4*)p;
            s0 += bf2f((ushort)v[0]); s1 += bf2f((ushort)v[1]);
            s2 += bf2f((ushort)v[2]); s3 += bf2f((ushort)v[3]);
        }
        xr[(g * 4 + 0) * NM + m] = s0;
        xr[(g * 4 + 1) * NM + m] = s1;
        xr[(g * 4 + 2) * NM + m] = s2;
        xr[(g * 4 + 3) * NM + m] = s3;
    }
    __syncthreads();

    {
        float acc[16];
        const float bias = ob1[t];
#pragma unroll
        for (int r = 0; r < 16; ++r) acc[r] = bias;
        const float* wrow = ow1 + (size_t)t * NM;
#pragma unroll 2
        for (int mq = 0; mq < NM / 4; ++mq) {
            const float4 w = ldg4(wrow + mq * 4);
#pragma unroll
            for (int r = 0; r < 16; ++r) {
                const float4 xv = *reinterpret_cast<const float4*>(&xr[r * NM + mq * 4]);
                acc[r] += xv.x * w.x + xv.y * w.y + xv.z * w.z + xv.w * w.w;
            }
        }
#pragma unroll
        for (int r = 0; r < 16; ++r) h1[r * NOH + t] = fmaxf(acc[r], 0.f);
    }
    __syncthreads();

    {
        float acc[16];
        const float bias = ob2[t];
#pragma unroll
        for (int r = 0; r < 16; ++r) acc[r] = bias;
        const float* wrow = ow2 + (size_t)t * NOH;
#pragma unroll 2
        for (int hq = 0; hq < NOH / 4; ++hq) {
            const float4 w = ldg4(wrow + hq * 4);
#pragma unroll
            for (int r = 0; r < 16; ++r) {
                const float4 hv = *reinterpret_cast<const float4*>(&h1[r * NOH + hq * 4]);
                acc[r] += hv.x * w.x + hv.y * w.y + hv.z * w.z + hv.w * w.w;
            }
        }
#pragma unroll
        for (int r = 0; r < 16; ++r) h2[r * NOH + t] = fmaxf(acc[r], 0.f);
    }
    __syncthreads();

    {
        const int d  = t & 63;
        const int rg = t >> 6;
        float acc[4] = {0.f, 0.f, 0.f, 0.f};
        const float* wrow = ow3 + (size_t)d * NOH;
#pragma unroll 2
        for (int hq = 0; hq < NOH / 4; ++hq) {
            const float4 w = ldg4(wrow + hq * 4);
#pragma unroll
            for (int r = 0; r < 4; ++r) {
                const float4 hv = *reinterpret_cast<const float4*>(&h2[(rg * 4 + r) * NOH + hq * 4]);
                acc[r] += hv.x * w.x + hv.y * w.y + hv.z * w.z + hv.w * w.w;
            }
        }
        const float bias = ob3[d];
#pragma unroll
        for (int r = 0; r < 4; ++r) {
            const int n = n0 + rg * 4 + r;
            const size_t idx = ((size_t)b * NN + n) * ND + d;
            out[idx] = inputs[idx] + acc[r] + bias;
        }
    }
}

extern "C" void kernel_launch(void* const* d_in, const int* in_sizes, int n_in,
                              void* d_out, int out_size, void* d_ws, size_t ws_size,
                              hipStream_t stream)
{
    const float* inputs   = (const float*)d_in[0];
    const float* rel_rec  = (const float*)d_in[1];
    const float* rel_send = (const float*)d_in[2];
    const float* rel_type = (const float*)d_in[3];
    const float* w1  = (const float*)d_in[5];
    const float* b1  = (const float*)d_in[6];
    const float* w2  = (const float*)d_in[7];
    const float* b2  = (const float*)d_in[8];
    const float* w3  = (const float*)d_in[9];
    const float* b3  = (const float*)d_in[10];
    const float* w4  = (const float*)d_in[11];
    const float* b4  = (const float*)d_in[12];
    const float* ow1 = (const float*)d_in[13];
    const float* ob1 = (const float*)d_in[14];
    const float* ow2 = (const float*)d_in[15];
    const float* ob2 = (const float*)d_in[16];
    const float* ow3 = (const float*)d_in[17];
    const float* ob3 = (const float*)d_in[18];

    char* ws = (char*)d_ws;

    k_pre <<<dim3(382), dim3(256), 0, stream>>>(inputs, rel_rec, rel_send,
                                                w1, w3, ws);
    k_edge<<<dim3(512), dim3(512), 0, stream>>>(rel_type,
                                                b1, b2, b3, b4, w2, w4, ws);
    k_out <<<dim3(256), dim3(256), 0, stream>>>((const ushort*)ws, inputs,
                                                ow1, ob1, ow2, ob2, ow3, ob3,
                                                (float*)d_out);
}

// Round 9
// 177.732 us; speedup vs baseline: 1.4615x; 1.4615x over previous
//
#include <hip/hip_runtime.h>
#include <hip/hip_bf16.h>

#define NB 32
#define NN 128
#define NE 16256
#define ND 64
#define NHID 128
#define NM 128
#define NOH 256
#define NT 2
#define EHALF 8128
#define NTILE 127        // 64-edge tiles per half (127*64 == 8128 exactly)
#define TILE_E 64

typedef short s16x8 __attribute__((ext_vector_type(8)));
typedef short s16x4 __attribute__((ext_vector_type(4)));
typedef float f32x4 __attribute__((ext_vector_type(4)));

#define MFMA16(a, b, c) __builtin_amdgcn_mfma_f32_16x16x32_bf16((a), (b), (c), 0, 0, 0)

// ---- ws layout (bytes) ----
// partial: bf16 [256][m=128][n=128]
#define PARTIAL_SZ ((size_t)256 * 128 * 128 * 2)          //  8,388,608
#define WS_RS      (PARTIAL_SZ)                           // ushort[NE][128]
#define RS_SZ      ((size_t)NE * 128 * 2)                 //  4,161,536
#define WS_RRT     (WS_RS + RS_SZ)                        // ushort[128][NE]
#define RRT_SZ     ((size_t)128 * NE * 2)                 //  4,161,536
#define WS_IWA     (WS_RRT + RRT_SZ)                      // ushort[b][half][it][h=128][n=128]
#define IWA_SZ     ((size_t)NB * 2 * 2 * 128 * 128 * 2)   //  8,388,608
// total = 25.1 MB (<= proven 32 MB)

__device__ __forceinline__ ushort f2bf(float x) {
    uint u = __float_as_uint(x);
    return (ushort)((u + 0x7fffu + ((u >> 16) & 1u)) >> 16);
}
__device__ __forceinline__ float bf2f(ushort h) {
    return __uint_as_float(((uint)h) << 16);
}
__device__ __forceinline__ float4 ldg4(const float* p) {
    return *reinterpret_cast<const float4*>(p);
}
// pack 2 f32 -> 2 bf16 in one dword (RNE), single VALU op
__device__ __forceinline__ uint cvtpk(float lo, float hi) {
    uint r;
    asm("v_cvt_pk_bf16_f32 %0, %1, %2" : "=v"(r) : "v"(lo), "v"(hi));
    return r;
}
// full-granule XOR swizzle for 256B rows: byte ^= (row&15)<<4
__device__ __forceinline__ char* swz16(void* base, int row, int bir) {
    return (char*)base + row * 256 + (bir ^ ((row & 15) << 4));
}
__device__ __forceinline__ const char* swz16c(const void* base, int row, int bir) {
    return (const char*)base + row * 256 + (bir ^ ((row & 15) << 4));
}
// 8-granule XOR swizzle for 128B rows: byte ^= (row&7)<<4
__device__ __forceinline__ char* swz8(void* base, int row, int bir) {
    return (char*)base + row * 128 + (bir ^ ((row & 7) << 4));
}
__device__ __forceinline__ const char* swz8c(const void* base, int row, int bir) {
    return (const char*)base + row * 128 + (bir ^ ((row & 7) << 4));
}
// async 16B global->LDS (dest lane-linear; source pre-swizzled per G21)
__device__ __forceinline__ void gload16(const void* g, void* l) {
    __builtin_amdgcn_global_load_lds(
        (const __attribute__((address_space(1))) void*)g,
        (__attribute__((address_space(3))) void*)l, 16, 0, 0);
}

// ---------------------------------------------------------------------------
// k_pre: fused conversions + inpWA precompute.
// blocks 0..126: rrT transpose+convert; 127..253: rs convert;
// blocks 254..381: inpWA[b][half][it] = (inp[b] @ WA^T) in bf16 [h][n]
// ---------------------------------------------------------------------------
__global__ __launch_bounds__(256)
void k_pre(const float* __restrict__ inputs,
           const float* __restrict__ rel_rec, const float* __restrict__ rel_send,
           const float* __restrict__ w1, const float* __restrict__ w3,
           char* __restrict__ ws)
{
    ushort* rs  = (ushort*)(ws + WS_RS);
    ushort* rrT = (ushort*)(ws + WS_RRT);
    const int t = threadIdx.x;
    const int blk = blockIdx.x;
    __shared__ float lds[128][65];

    if (blk < 127) {                       // rrT: transpose rel_rec -> [n][e] bf16
        const int eb = blk;
        for (int nh = 0; nh < 2; ++nh) {
            __syncthreads();
            for (int i = t; i < 128 * 64; i += 256) {
                int e = i >> 6, n = i & 63;
                lds[e][n] = rel_rec[(size_t)(eb * 128 + e) * 128 + nh * 64 + n];
            }
            __syncthreads();
            for (int i = t; i < 64 * 128; i += 256) {
                int n = i >> 7, e = i & 127;
                rrT[(size_t)(nh * 64 + n) * NE + eb * 128 + e] = f2bf(lds[e][n]);
            }
        }
    } else if (blk < 254) {                // rs: straight convert
        const int eb = blk - 127;
        const float4* src = (const float4*)(rel_send + (size_t)eb * 16384);
        for (int i = t; i < 4096; i += 256) {
            float4 v = src[i];
            ushort4 o;
            o.x = f2bf(v.x); o.y = f2bf(v.y); o.z = f2bf(v.z); o.w = f2bf(v.w);
            *(ushort4*)(rs + (size_t)eb * 16384 + (size_t)i * 4) = o;
        }
    } else {                               // inpWA precompute (MFMA)
        ushort* iwa = (ushort*)(ws + WS_IWA);
        const int wg = blk - 254;          // 0..127
        const int b = wg >> 2, half = (wg >> 1) & 1, it = wg & 1;
        const float* WA  = (half ? w3 : w1) + (size_t)it * NHID * ND;
        const float* inp = inputs + (size_t)b * NN * ND;
        ushort* dst = iwa + (size_t)wg * NHID * NN;    // [h][n]

        const int lane = t & 63, wave = t >> 6;
        const int l16 = lane & 15, l4 = lane >> 4;

        for (int hh = 0; hh < 2; ++hh) {
            const int ht = wave * 2 + hh;
            s16x8 bf[2];
#pragma unroll
            for (int ks = 0; ks < 2; ++ks) {
                const float* p = WA + (size_t)(ht * 16 + l16) * ND + ks * 32 + l4 * 8;
                float4 u = ldg4(p), v = ldg4(p + 4);
                s16x8 f;
                f[0] = (short)f2bf(u.x); f[1] = (short)f2bf(u.y);
                f[2] = (short)f2bf(u.z); f[3] = (short)f2bf(u.w);
                f[4] = (short)f2bf(v.x); f[5] = (short)f2bf(v.y);
                f[6] = (short)f2bf(v.z); f[7] = (short)f2bf(v.w);
                bf[ks] = f;
            }
            for (int nt = 0; nt < 8; ++nt) {
                s16x8 af[2];
#pragma unroll
                for (int ks = 0; ks < 2; ++ks) {
                    const float* p = inp + (size_t)(nt * 16 + l16) * ND + ks * 32 + l4 * 8;
                    float4 u = ldg4(p), v = ldg4(p + 4);
                    s16x8 f;
                    f[0] = (short)f2bf(u.x); f[1] = (short)f2bf(u.y);
                    f[2] = (short)f2bf(u.z); f[3] = (short)f2bf(u.w);
                    f[4] = (short)f2bf(v.x); f[5] = (short)f2bf(v.y);
                    f[6] = (short)f2bf(v.z); f[7] = (short)f2bf(v.w);
                    af[ks] = f;
                }
                f32x4 c = (f32x4){0.f, 0.f, 0.f, 0.f};
                c = MFMA16(af[0], bf[0], c);
                c = MFMA16(af[1], bf[1], c);
                s16x4 o;
                o[0] = (short)f2bf(c[0]); o[1] = (short)f2bf(c[1]);
                o[2] = (short)f2bf(c[2]); o[3] = (short)f2bf(c[3]);
                *(s16x4*)&dst[(size_t)(ht * 16 + l16) * NN + nt * 16 + l4 * 4] = o;
            }
        }
    }
}

// ---------------------------------------------------------------------------
// k_edge: grid 256 = b*8 + half*4 + chunk(4). block 512 (8 waves), 1 block/CU.
// Round-5 schedule (ONE barrier per tile), gload_lds staging, (row&15)<<4
// swizzle on 256B-row arrays (conflict-free H C-writes + A-reads).
//   P(t): issue gload rr(t)->rr[buf], rs(t+1)->rs[nbuf]; rt(t); H-phase
//         (read rs[buf], write H[buf])                          | barrier
//   Q(t): M-phase (read H[buf], wB regs) -> wave-private Mt roundtrip ->
//         agg += rrT@M (read rr[buf])
// ---------------------------------------------------------------------------
__global__ __launch_bounds__(512, 1)
void k_edge(const float* __restrict__ rel_type,
            const float* __restrict__ b1, const float* __restrict__ b2,
            const float* __restrict__ b3, const float* __restrict__ b4,
            const float* __restrict__ w2, const float* __restrict__ w4,
            char* __restrict__ ws)
{
    const ushort* rsg = (const ushort*)(ws + WS_RS);
    const ushort* rrT = (const ushort*)(ws + WS_RRT);
    const ushort* iwa = (const ushort*)(ws + WS_IWA);
    ushort* partial   = (ushort*)ws;

    const int tid  = threadIdx.x;
    const int wave = tid >> 6;
    const int lane = tid & 63;
    const int l16  = lane & 15;
    const int l4   = lane >> 4;

    const int wg    = blockIdx.x;
    const int b     = wg >> 3;
    const int half  = (wg >> 2) & 1;
    const int chunk = wg & 3;

    const float* BA    = half ? b3 : b1;
    const float* BB    = half ? b4 : b2;
    const float* WBsrc = half ? w4 : w2;

    __shared__ ushort H_s[2][2][64 * 128];  // 64 KB (buf, it), 256B rows
    __shared__ ushort rs_s[2][64 * 128];    // 32 KB, 256B rows
    __shared__ ushort rr_s[2][128 * 64];    // 32 KB, 128B rows
    __shared__ ushort Mt_s[128 * 64];       // 16 KB, 128B rows, wave-private
    __shared__ float  rt_s[2][128];         //  1 KB
    // total 145 KB -> 1 block/CU (structural; occupancy chase abandoned)

    // persistent fragments: wIW 32 + wB 32 + agg 32
    s16x8 wIW[2][4];
    const ushort* iwb = iwa + (size_t)((b * 2 + half) * 2) * NHID * NN;
#pragma unroll
    for (int it = 0; it < 2; ++it)
#pragma unroll
        for (int ks = 0; ks < 4; ++ks)
            wIW[it][ks] = *(const s16x8*)(iwb + (size_t)it * NHID * NN +
                                          (size_t)(wave * 16 + l16) * NN + ks * 32 + l4 * 8);
    s16x8 wB[2][4];
#pragma unroll
    for (int it = 0; it < 2; ++it)
#pragma unroll
        for (int ks = 0; ks < 4; ++ks) {
            const float* p = WBsrc + (size_t)(it * NM + wave * 16 + l16) * NHID + ks * 32 + l4 * 8;
            float4 u = ldg4(p), v = ldg4(p + 4);
            s16x8 f;
            f[0] = (short)f2bf(u.x); f[1] = (short)f2bf(u.y);
            f[2] = (short)f2bf(u.z); f[3] = (short)f2bf(u.w);
            f[4] = (short)f2bf(v.x); f[5] = (short)f2bf(v.y);
            f[6] = (short)f2bf(v.z); f[7] = (short)f2bf(v.w);
            wB[it][ks] = f;
        }
    float biasA[2] = {BA[wave * 16 + l16], BA[NHID + wave * 16 + l16]};
    float biasB[2] = {BB[wave * 16 + l16], BB[NM + wave * 16 + l16]};

    f32x4 agg[8];
#pragma unroll
    for (int r = 0; r < 8; ++r) agg[r] = (f32x4){0.f, 0.f, 0.f, 0.f};

    const int t0 = chunk * 32;
    const int t1 = (t0 + 32 < NTILE) ? (t0 + 32) : NTILE;

    // ---- prologue: stage rs(t0) into buf0 (source pre-swizzled, dest linear)
    {
        const int ebase0 = half * EHALF + t0 * TILE_E;
#pragma unroll
        for (int s = 0; s < 2; ++s) {
            const int i = s * 512 + tid;
            const int e = i >> 4, c = i & 15;
            const int cp = c ^ (e & 15);
            gload16(rsg + (size_t)(ebase0 + e) * 128 + cp * 8, (char*)&rs_s[0][0] + i * 16);
        }
    }
    __syncthreads();

    for (int t = t0; t < t1; ++t) {
        const int buf  = (t - t0) & 1;
        const int nbuf = buf ^ 1;
        const int ebase = half * EHALF + t * TILE_E;
        const bool do_next = (t + 1) < t1;

        // ---- P(t) ----
        // (a) issue rr(t) -> rr_s[buf]
#pragma unroll
        for (int s = 0; s < 2; ++s) {
            const int j = s * 512 + tid;
            const int n = j >> 3, c = j & 7;
            const int cp = c ^ (n & 7);
            gload16(rrT + (size_t)n * NE + ebase + cp * 8, (char*)&rr_s[buf][0] + j * 16);
        }
        // (b) issue rs(t+1) -> rs_s[nbuf]
        if (do_next) {
            const int ebn = ebase + TILE_E;
#pragma unroll
            for (int s = 0; s < 2; ++s) {
                const int i = s * 512 + tid;
                const int e = i >> 4, c = i & 15;
                const int cp = c ^ (e & 15);
                gload16(rsg + (size_t)(ebn + e) * 128 + cp * 8, (char*)&rs_s[nbuf][0] + i * 16);
            }
        }
        // (c) rt stage (contiguous)
        if (tid < 128)
            rt_s[buf][tid] = rel_type[((size_t)b * NE + ebase + (tid >> 1)) * NT + (tid & 1)];

        // (d) H-phase: H[it] = relu(RS @ inpWA[it] + bA[it]) -> H_s[buf][it]
#pragma unroll
        for (int et = 0; et < 4; ++et) {
            const int erow = et * 16 + l16;
            s16x8 a0 = *(const s16x8*)swz16c(&rs_s[buf][0], erow, 0 * 64 + l4 * 16);
            s16x8 a1 = *(const s16x8*)swz16c(&rs_s[buf][0], erow, 1 * 64 + l4 * 16);
            s16x8 a2 = *(const s16x8*)swz16c(&rs_s[buf][0], erow, 2 * 64 + l4 * 16);
            s16x8 a3 = *(const s16x8*)swz16c(&rs_s[buf][0], erow, 3 * 64 + l4 * 16);
#pragma unroll
            for (int it = 0; it < 2; ++it) {
                f32x4 c = (f32x4){0.f, 0.f, 0.f, 0.f};
                __builtin_amdgcn_s_setprio(1);
                c = MFMA16(a0, wIW[it][0], c);
                c = MFMA16(a1, wIW[it][1], c);
                c = MFMA16(a2, wIW[it][2], c);
                c = MFMA16(a3, wIW[it][3], c);
                __builtin_amdgcn_s_setprio(0);
#pragma unroll
                for (int r = 0; r < 4; ++r) {
                    const int er = et * 16 + l4 * 4 + r;
                    *(ushort*)swz16(&H_s[buf][it][0], er, (wave * 16 + l16) * 2) =
                        f2bf(fmaxf(c[r] + biasA[it], 0.f));
                }
            }
        }
        __syncthreads();                                   // the ONE barrier

        // ---- Q(t): M then agg ----
        float macc[4][4];
#pragma unroll
        for (int et = 0; et < 4; ++et)
#pragma unroll
            for (int r = 0; r < 4; ++r) macc[et][r] = 0.f;

#pragma unroll
        for (int et = 0; et < 4; ++et) {
            const int e = et * 16 + l16;
            float2 rtv[4];
#pragma unroll
            for (int r = 0; r < 4; ++r)
                rtv[r] = *(const float2*)&rt_s[buf][(et * 16 + l4 * 4 + r) * 2];
#pragma unroll
            for (int it = 0; it < 2; ++it) {
                f32x4 c = (f32x4){0.f, 0.f, 0.f, 0.f};
                __builtin_amdgcn_s_setprio(1);
#pragma unroll
                for (int ks = 0; ks < 4; ++ks) {
                    s16x8 a = *(const s16x8*)swz16c(&H_s[buf][it][0], e, ks * 64 + l4 * 16);
                    c = MFMA16(a, wB[it][ks], c);
                }
                __builtin_amdgcn_s_setprio(0);
#pragma unroll
                for (int r = 0; r < 4; ++r)
                    macc[et][r] += fmaxf(c[r] + biasB[it], 0.f) * (it ? rtv[r].y : rtv[r].x);
            }
        }

        // Mt: wave-private roundtrip (wave w touches only rows 16w..16w+15)
        {
            const int m = wave * 16 + l16;
#pragma unroll
            for (int et = 0; et < 4; ++et) {
                uint2 v;
                v.x = cvtpk(macc[et][0], macc[et][1]);
                v.y = cvtpk(macc[et][2], macc[et][3]);
                *(uint2*)swz8(Mt_s, m, et * 32 + l4 * 8) = v;
            }
            s16x8 bb0 = *(const s16x8*)swz8c(Mt_s, m, 0 * 64 + l4 * 16);
            s16x8 bb1 = *(const s16x8*)swz8c(Mt_s, m, 1 * 64 + l4 * 16);
            __builtin_amdgcn_s_setprio(1);
#pragma unroll
            for (int nt = 0; nt < 8; ++nt) {
                const int n = nt * 16 + l16;
                s16x8 a0 = *(const s16x8*)swz8c(&rr_s[buf][0], n, 0 * 64 + l4 * 16);
                s16x8 a1 = *(const s16x8*)swz8c(&rr_s[buf][0], n, 1 * 64 + l4 * 16);
                agg[nt] = MFMA16(a0, bb0, agg[nt]);
                agg[nt] = MFMA16(a1, bb1, agg[nt]);
            }
            __builtin_amdgcn_s_setprio(0);
        }
    }

    // store bf16 partialT [wg][m][n] (cvt_pk pairs)
    {
        ushort* dst = partial + (size_t)wg * (NN * NM);
        const int m = wave * 16 + l16;
#pragma unroll
        for (int nt = 0; nt < 8; ++nt) {
            uint2 v;
            v.x = cvtpk(agg[nt][0], agg[nt][1]);
            v.y = cvtpk(agg[nt][2], agg[nt][3]);
            *(uint2*)&dst[(size_t)m * NN + nt * 16 + l4 * 4] = v;
        }
    }
}

// ---------------------------------------------------------------------------
// k_out: reduce 8 bf16 partials -> node MLP 128->256->256->64 + residual
// ---------------------------------------------------------------------------
__global__ __launch_bounds__(256)
void k_out(const ushort* __restrict__ partial,
           const float* __restrict__ inputs,
           const float* __restrict__ ow1, const float* __restrict__ ob1,
           const float* __restrict__ ow2, const float* __restrict__ ob2,
           const float* __restrict__ ow3, const float* __restrict__ ob3,
           float* __restrict__ out)
{
    const int t  = threadIdx.x;
    const int wg = blockIdx.x;      // 0..255
    const int b  = wg >> 3;
    const int n0 = (wg & 7) * 16;

    __shared__ float xr[16 * NM];
    __shared__ float h1[16 * NOH];
    __shared__ float h2[16 * NOH];

    // reduce 8 partials (transposed layout [m][n])
    for (int u = t; u < 512; u += 256) {
        const int m = u >> 2, g = u & 3;
        float s0 = 0.f, s1 = 0.f, s2 = 0.f, s3 = 0.f;
#pragma unroll
        for (int c = 0; c < 8; ++c) {
            const ushort* p = partial + ((size_t)(b * 8 + c)) * (NN * NM) +
                              (size_t)m * NN + n0 + g * 4;
            s16x4 v = *(const s16x4*)p;
            s0 += bf2f((ushort)v[0]); s1 += bf2f((ushort)v[1]);
            s2 += bf2f((ushort)v[2]); s3 += bf2f((ushort)v[3]);
        }
        xr[(g * 4 + 0) * NM + m] = s0;
        xr[(g * 4 + 1) * NM + m] = s1;
        xr[(g * 4 + 2) * NM + m] = s2;
        xr[(g * 4 + 3) * NM + m] = s3;
    }
    __syncthreads();

    {
        float acc[16];
        const float bias = ob1[t];
#pragma unroll
        for (int r = 0; r < 16; ++r) acc[r] = bias;
        const float* wrow = ow1 + (size_t)t * NM;
#pragma unroll 2
        for (int mq = 0; mq < NM / 4; ++mq) {
            const float4 w = ldg4(wrow + mq * 4);
#pragma unroll
            for (int r = 0; r < 16; ++r) {
                const float4 xv = *reinterpret_cast<const float4*>(&xr[r * NM + mq * 4]);
                acc[r] += xv.x * w.x + xv.y * w.y + xv.z * w.z + xv.w * w.w;
            }
        }
#pragma unroll
        for (int r = 0; r < 16; ++r) h1[r * NOH + t] = fmaxf(acc[r], 0.f);
    }
    __syncthreads();

    {
        float acc[16];
        const float bias = ob2[t];
#pragma unroll
        for (int r = 0; r < 16; ++r) acc[r] = bias;
        const float* wrow = ow2 + (size_t)t * NOH;
#pragma unroll 2
        for (int hq = 0; hq < NOH / 4; ++hq) {
            const float4 w = ldg4(wrow + hq * 4);
#pragma unroll
            for (int r = 0; r < 16; ++r) {
                const float4 hv = *reinterpret_cast<const float4*>(&h1[r * NOH + hq * 4]);
                acc[r] += hv.x * w.x + hv.y * w.y + hv.z * w.z + hv.w * w.w;
            }
        }
#pragma unroll
        for (int r = 0; r < 16; ++r) h2[r * NOH + t] = fmaxf(acc[r], 0.f);
    }
    __syncthreads();

    {
        const int d  = t & 63;
        const int rg = t >> 6;
        float acc[4] = {0.f, 0.f, 0.f, 0.f};
        const float* wrow = ow3 + (size_t)d * NOH;
#pragma unroll 2
        for (int hq = 0; hq < NOH / 4; ++hq) {
            const float4 w = ldg4(wrow + hq * 4);
#pragma unroll
            for (int r = 0; r < 4; ++r) {
                const float4 hv = *reinterpret_cast<const float4*>(&h2[(rg * 4 + r) * NOH + hq * 4]);
                acc[r] += hv.x * w.x + hv.y * w.y + hv.z * w.z + hv.w * w.w;
            }
        }
        const float bias = ob3[d];
#pragma unroll
        for (int r = 0; r < 4; ++r) {
            const int n = n0 + rg * 4 + r;
            const size_t idx = ((size_t)b * NN + n) * ND + d;
            out[idx] = inputs[idx] + acc[r] + bias;
        }
    }
}

extern "C" void kernel_launch(void* const* d_in, const int* in_sizes, int n_in,
                              void* d_out, int out_size, void* d_ws, size_t ws_size,
                              hipStream_t stream)
{
    const float* inputs   = (const float*)d_in[0];
    const float* rel_rec  = (const float*)d_in[1];
    const float* rel_send = (const float*)d_in[2];
    const float* rel_type = (const float*)d_in[3];
    const float* w1  = (const float*)d_in[5];
    const float* b1  = (const float*)d_in[6];
    const float* w2  = (const float*)d_in[7];
    const float* b2  = (const float*)d_in[8];
    const float* w3  = (const float*)d_in[9];
    const float* b3  = (const float*)d_in[10];
    const float* w4  = (const float*)d_in[11];
    const float* b4  = (const float*)d_in[12];
    const float* ow1 = (const float*)d_in[13];
    const float* ob1 = (const float*)d_in[14];
    const float* ow2 = (const float*)d_in[15];
    const float* ob2 = (const float*)d_in[16];
    const float* ow3 = (const float*)d_in[17];
    const float* ob3 = (const float*)d_in[18];

    char* ws = (char*)d_ws;

    k_pre <<<dim3(382), dim3(256), 0, stream>>>(inputs, rel_rec, rel_send,
                                                w1, w3, ws);
    k_edge<<<dim3(256), dim3(512), 0, stream>>>(rel_type,
                                                b1, b2, b3, b4, w2, w4, ws);
    k_out <<<dim3(256), dim3(256), 0, stream>>>((const ushort*)ws, inputs,
                                                ow1, ob1, ow2, ob2, ow3, ob3,
                                                (float*)d_out);
}